// Round 11
// baseline (2442.830 us; speedup 1.0000x reference)
//
#include <hip/hip_runtime.h>
#include <hip/hip_bf16.h>

#define BB 128
#define TT 2048
#define HH 64
#define BT (BB * TT)
#define EPS_BN 1e-5f

typedef unsigned short ushort_t;
typedef short s8v __attribute__((ext_vector_type(8)));   // 8 bf16 as shorts (4 VGPRs)
typedef float f4v __attribute__((ext_vector_type(4)));   // MFMA accum

__device__ __forceinline__ float gelu_exact(float x) {
    return 0.5f * x * (1.0f + erff(x * 0.70710678118654752440f));
}
__device__ __forceinline__ ushort_t f2bf(float v) {
    __hip_bfloat16 h = __float2bfloat16(v);
    return *reinterpret_cast<ushort_t*>(&h);
}
__device__ __forceinline__ float lse2(float a, float b) {
    float m = fmaxf(a, b);
    return m + log1pf(__expf(-fabsf(a - b)));
}

// ================= Kernel A: conv stack (MFMA bf16) -> y bf16 [B*T][64] =================
__global__ __launch_bounds__(256, 4) void conv_kernel(
    const float* __restrict__ x, const float* __restrict__ cw1, const float* __restrict__ cb1,
    const float* __restrict__ cwr, const float* __restrict__ cbr,
    const float* __restrict__ bn_g, const float* __restrict__ bn_b,
    const float* __restrict__ bn_m, const float* __restrict__ bn_v,
    ushort_t* __restrict__ y) {
    __shared__ ushort_t s_wc[3 * 64 * 64];   // swizzled bf16 conv weights (24 KB)
    __shared__ float s_l1[64 * 4];
    __shared__ float s_sc[256], s_sh[256];
    __shared__ float s_cb[192];
    __shared__ ushort_t s_act[4][1024];      // per-wave 16x64 bf16 act (8 KB)

    int tid = threadIdx.x;
    for (int i = tid; i < 3 * 64 * 64; i += 256) {
        int row = (i >> 6) & 63, col = i & 63;
        unsigned by = (unsigned)((i >> 6) * 128 + col * 2) ^ (unsigned)((row & 7) << 4);
        s_wc[by >> 1] = f2bf(cwr[i]);
    }
    if (tid < 64) {
        s_l1[tid * 4 + 0] = cw1[tid * 2 + 0];
        s_l1[tid * 4 + 1] = cw1[tid * 2 + 1];
        s_l1[tid * 4 + 2] = cb1[tid];
    }
    if (tid < 256) {
        float sc = bn_g[tid] * rsqrtf(bn_v[tid] + EPS_BN);
        s_sc[tid] = sc;
        s_sh[tid] = bn_b[tid] - bn_m[tid] * sc;
    }
    if (tid < 192) s_cb[tid] = cbr[tid];
    __syncthreads();

    int wid = tid >> 6, l = tid & 63;
    int lrow = l & 15, lgrp = l >> 4;
    ushort_t* act = s_act[wid];
    int gwave = blockIdx.x * 4 + wid;        // 1024 blocks * 4 waves = 4096

    for (int strip = gwave; strip < 16384; strip += 4096) {
        int p0 = strip << 4;
        float2 xv = ((const float2*)x)[p0 + lrow];
        s8v fa0, fa1;
#pragma unroll
        for (int j = 0; j < 8; ++j) {
            int c0 = lgrp * 8 + j, c1 = 32 + c0;
            float t0 = s_l1[c0 * 4] * xv.x + s_l1[c0 * 4 + 1] * xv.y + s_l1[c0 * 4 + 2];
            t0 = gelu_exact(t0) * s_sc[c0] + s_sh[c0];
            fa0[j] = (short)f2bf(t0);
            float t1 = s_l1[c1 * 4] * xv.x + s_l1[c1 * 4 + 1] * xv.y + s_l1[c1 * 4 + 2];
            t1 = gelu_exact(t1) * s_sc[c1] + s_sh[c1];
            fa1[j] = (short)f2bf(t1);
        }
#pragma unroll
        for (int L = 0; L < 3; ++L) {
            f4v acc[4];
#pragma unroll
            for (int nt = 0; nt < 4; ++nt) {
                acc[nt] = (f4v){0.f, 0.f, 0.f, 0.f};
                int row = nt * 16 + lrow;
                unsigned b0 = (unsigned)(L * 8192 + row * 128 + lgrp * 16) ^ (unsigned)((row & 7) << 4);
                unsigned b1 = (unsigned)(L * 8192 + row * 128 + lgrp * 16 + 64) ^ (unsigned)((row & 7) << 4);
                s8v fb0 = *(const s8v*)((const char*)s_wc + b0);
                s8v fb1 = *(const s8v*)((const char*)s_wc + b1);
                acc[nt] = __builtin_amdgcn_mfma_f32_16x16x32_bf16(fa0, fb0, acc[nt], 0, 0, 0);
                acc[nt] = __builtin_amdgcn_mfma_f32_16x16x32_bf16(fa1, fb1, acc[nt], 0, 0, 0);
            }
#pragma unroll
            for (int nt = 0; nt < 4; ++nt) {
                int ch = nt * 16 + lrow;
#pragma unroll
                for (int i = 0; i < 4; ++i) {
                    float v = acc[nt][i] + s_cb[L * 64 + ch];
                    v = gelu_exact(v) * s_sc[(L + 1) * 64 + ch] + s_sh[(L + 1) * 64 + ch];
                    int pos = lgrp * 4 + i;
                    unsigned by = (unsigned)(pos * 128 + ch * 2) ^ (unsigned)((pos & 7) << 4);
                    *(ushort_t*)((char*)act + by) = f2bf(v);
                }
            }
            if (L < 2) {
                unsigned r0 = (unsigned)(lrow * 128 + lgrp * 16) ^ (unsigned)((lrow & 7) << 4);
                unsigned r1 = (unsigned)(lrow * 128 + lgrp * 16 + 64) ^ (unsigned)((lrow & 7) << 4);
                fa0 = *(const s8v*)((const char*)act + r0);
                fa1 = *(const s8v*)((const char*)act + r1);
            }
        }
        int prow = l >> 2, pc = l & 3;
        unsigned so0 = (unsigned)(prow * 128 + pc * 32) ^ (unsigned)((prow & 7) << 4);
        unsigned so1 = (unsigned)(prow * 128 + pc * 32 + 16) ^ (unsigned)((prow & 7) << 4);
        s8v v0 = *(const s8v*)((const char*)act + so0);
        s8v v1 = *(const s8v*)((const char*)act + so1);
        char* yb = (char*)y + (size_t)(p0 + prow) * 128 + pc * 32;
        *(s8v*)yb = v0;
        *(s8v*)(yb + 16) = v1;
    }
}

// ===== Kernel B: BiLSTM — ONE WAVE per (dir,b) chain, barrier-free, shuffle-free =====
// whh in 256 f32 VGPRs per lane (lane = unit u, all 4 gates in-lane).
// z = Wih.y via 32 bf16 MFMAs per 16-step strip (rows permuted r=u*4+g so each lane's
// D-float4 = its 4 gates); h ring in LDS: 1 ds_write + broadcast ds_reads per step,
// same-wave DS FIFO ordering => no __syncthreads anywhere.
__global__ __launch_bounds__(64, 1) void lstm_kernel(
    const ushort_t* __restrict__ y,
    const float* __restrict__ whh_f, const float* __restrict__ whh_b,
    const float* __restrict__ wih_f, const float* __restrict__ wih_b,
    const float* __restrict__ bih_f, const float* __restrict__ bhh_f,
    const float* __restrict__ bih_b, const float* __restrict__ bhh_b,
    const float* __restrict__ fc_w, float* __restrict__ em_ws) {
    __shared__ ushort_t s_wih[256 * 64];     // 32 KB swizzled bf16, rows r = u*4+g
    __shared__ float zlds[16][260];          // 16.6 KB  z[t][u*4+g] (+pad)
    __shared__ float ring[32][72];           // 9 KB   h f32, 2 strips x 16 slots
    __shared__ ushort_t embuf[2][16][72];    // 4.5 KB h bf16 for emission MFMA

    int bid = blockIdx.x;
    int d = bid >> 7, b = bid & 127;
    const float* whh = d ? whh_b : whh_f;
    const float* wih = d ? wih_b : wih_f;
    const float* bih = d ? bih_b : bih_f;
    const float* bhh = d ? bhh_b : bhh_f;

    int l = threadIdx.x;
    int lc = l & 15, lg = l >> 4;

    // stage wih (permuted rows, swizzled)
    for (int i = l; i < 256 * 64; i += 64) {
        int r = i >> 6, k = i & 63, u = r >> 2, g = r & 3;
        unsigned by = (unsigned)(r * 128 + k * 2) ^ (unsigned)((r & 7) << 4);
        s_wih[by >> 1] = f2bf(wih[(size_t)(g * 64 + u) * 64 + k]);
    }
    for (int i = l; i < 32 * 72; i += 64) (&ring[0][0])[i] = 0.f;

    // whh rows for this lane's unit u=l, all 4 gates, f32 in VGPRs
    float4 wr0[16], wr1[16], wr2[16], wr3[16];
#pragma unroll
    for (int m = 0; m < 16; ++m) {
        wr0[m] = *(const float4*)(whh + (size_t)(0 * 64 + l) * 64 + m * 4);
        wr1[m] = *(const float4*)(whh + (size_t)(1 * 64 + l) * 64 + m * 4);
        wr2[m] = *(const float4*)(whh + (size_t)(2 * 64 + l) * 64 + m * 4);
        wr3[m] = *(const float4*)(whh + (size_t)(3 * 64 + l) * 64 + m * 4);
    }
    float4 zb;
    zb.x = bih[0 * 64 + l] + bhh[0 * 64 + l];
    zb.y = bih[1 * 64 + l] + bhh[1 * 64 + l];
    zb.z = bih[2 * 64 + l] + bhh[2 * 64 + l];
    zb.w = bih[3 * 64 + l] + bhh[3 * 64 + l];

    // emission A-fragment (classes 0,1 in rows 0,1; rest zero)
    s8v femA0, femA1;
#pragma unroll
    for (int j = 0; j < 8; ++j) {
        femA0[j] = (lc < 2) ? (short)f2bf(fc_w[lc * 128 + d * 64 + lg * 8 + j]) : (short)0;
        femA1[j] = (lc < 2) ? (short)f2bf(fc_w[lc * 128 + d * 64 + 32 + lg * 8 + j]) : (short)0;
    }

    int t0 = d ? (TT - 1) : 0;
    int dstep = d ? -1 : 1;
    const char* ybase = (const char*)y + (size_t)b * TT * 128;
    float2* emv = (float2*)em_ws;

    // prologue: strip-0 y B-fragments (col = timestep, k = feature)
    s8v yc0, yc1;
    {
        int t = t0 + dstep * lc;
        const char* p = ybase + (size_t)t * 128 + lg * 16;
        yc0 = *(const s8v*)p;
        yc1 = *(const s8v*)(p + 64);
    }
    float cst = 0.f;

    for (int sp = 0; sp < 128; ++sp) {
        // ---- z-projection MFMA: 16 row-tiles, cols = 16 timesteps ----
#pragma unroll
        for (int n = 0; n < 16; ++n) {
            int r = 16 * n + lc;
            unsigned a0b = (unsigned)(r * 128 + lg * 16) ^ (unsigned)((r & 7) << 4);
            unsigned a1b = (unsigned)(r * 128 + lg * 16 + 64) ^ (unsigned)((r & 7) << 4);
            s8v fb0 = *(const s8v*)((const char*)s_wih + a0b);
            s8v fb1 = *(const s8v*)((const char*)s_wih + a1b);
            f4v acc = (f4v){0.f, 0.f, 0.f, 0.f};
            acc = __builtin_amdgcn_mfma_f32_16x16x32_bf16(fb0, yc0, acc, 0, 0, 0);
            acc = __builtin_amdgcn_mfma_f32_16x16x32_bf16(fb1, yc1, acc, 0, 0, 0);
            *(float4*)&zlds[lc][(4 * n + lg) * 4] = make_float4(acc[0], acc[1], acc[2], acc[3]);
        }
        // ---- emission MFMA for previous strip (off critical path) ----
        if (sp > 0) {
            const ushort_t* eb = &embuf[(sp - 1) & 1][0][0];
            s8v hb0 = *(const s8v*)((const char*)eb + lc * 144 + lg * 16);
            s8v hb1 = *(const s8v*)((const char*)eb + lc * 144 + lg * 16 + 64);
            f4v a = (f4v){0.f, 0.f, 0.f, 0.f};
            a = __builtin_amdgcn_mfma_f32_16x16x32_bf16(femA0, hb0, a, 0, 0, 0);
            a = __builtin_amdgcn_mfma_f32_16x16x32_bf16(femA1, hb1, a, 0, 0, 0);
            if (lg == 0) {
                int t = t0 + dstep * ((sp - 1) * 16 + lc);
                emv[((size_t)d * TT + t) * BB + b] = make_float2(a[0], a[1]);
            }
        }
        // ---- prefetch next strip's y fragments (no barrier => no forced vmcnt drain) ----
        s8v yn0 = yc0, yn1 = yc1;
        if (sp + 1 < 128) {
            int t = t0 + dstep * ((sp + 1) * 16 + lc);
            const char* p = ybase + (size_t)t * 128 + lg * 16;
            yn0 = *(const s8v*)p;
            yn1 = *(const s8v*)(p + 64);
        }
        // ---- 16 recurrence steps (rolled loop; DS FIFO gives write->read ordering) ----
        for (int j = 0; j < 16; ++j) {
            int prev = (j == 0) ? ((((sp & 1) ^ 1) << 4) + 15) : (((sp & 1) << 4) + j - 1);
            float4 hh[16];
#pragma unroll
            for (int m = 0; m < 16; ++m) hh[m] = *(const float4*)&ring[prev][m * 4];
            float a0 = 0.f, a1 = 0.f, a2 = 0.f, a3 = 0.f;
#pragma unroll
            for (int m = 0; m < 16; ++m) {
                float4 h4 = hh[m];
                a0 += h4.x * wr0[m].x + h4.y * wr0[m].y + h4.z * wr0[m].z + h4.w * wr0[m].w;
                a1 += h4.x * wr1[m].x + h4.y * wr1[m].y + h4.z * wr1[m].z + h4.w * wr1[m].w;
                a2 += h4.x * wr2[m].x + h4.y * wr2[m].y + h4.z * wr2[m].z + h4.w * wr2[m].w;
                a3 += h4.x * wr3[m].x + h4.y * wr3[m].y + h4.z * wr3[m].z + h4.w * wr3[m].w;
            }
            float4 z4 = *(const float4*)&zlds[j][l * 4];
            a0 += z4.x + zb.x;
            a1 += z4.y + zb.y;
            a2 += z4.z + zb.z;
            a3 += z4.w + zb.w;
            float ig = 1.f / (1.f + __expf(-a0));
            float fg = 1.f / (1.f + __expf(-a1));
            float gg = 1.f - 2.f / (__expf(2.f * a2) + 1.f);
            float og = 1.f / (1.f + __expf(-a3));
            cst = fg * cst + ig * gg;
            float h = og * (1.f - 2.f / (__expf(2.f * cst) + 1.f));
            int slot = ((sp & 1) << 4) + j;
            ring[slot][l] = h;
            embuf[sp & 1][j][l] = f2bf(h);
        }
        yc0 = yn0;
        yc1 = yn1;
    }
    // emission for the last strip (sp = 127 -> embuf[1])
    {
        const ushort_t* eb = &embuf[1][0][0];
        s8v hb0 = *(const s8v*)((const char*)eb + lc * 144 + lg * 16);
        s8v hb1 = *(const s8v*)((const char*)eb + lc * 144 + lg * 16 + 64);
        f4v a = (f4v){0.f, 0.f, 0.f, 0.f};
        a = __builtin_amdgcn_mfma_f32_16x16x32_bf16(femA0, hb0, a, 0, 0, 0);
        a = __builtin_amdgcn_mfma_f32_16x16x32_bf16(femA1, hb1, a, 0, 0, 0);
        if (lg == 0) {
            int t = t0 + dstep * (127 * 16 + lc);
            emv[((size_t)d * TT + t) * BB + b] = make_float2(a[0], a[1]);
        }
    }
}

// ===== Kernel C: CRF via parallel log-semiring scan; block=b, thread=16-step chunk =====
__global__ __launch_bounds__(128) void crf_kernel(
    const float* __restrict__ em_ws, const int* __restrict__ tags,
    const float* __restrict__ fc_b, const float* __restrict__ crf_start,
    const float* __restrict__ crf_end, const float* __restrict__ crf_trans,
    float* __restrict__ nll_ws) {
    int b = blockIdx.x, c = threadIdx.x;
    float fb0 = fc_b[0], fb1 = fc_b[1];
    float t00 = crf_trans[0], t01 = crf_trans[1], t10 = crf_trans[2], t11 = crf_trans[3];
    const float2* p0 = (const float2*)em_ws;
    const float2* p1 = p0 + (size_t)TT * BB;
    const int* tg = tags + (size_t)b * TT;

    int tbeg = 1 + 16 * c;
    int tend = min(TT, tbeg + 16);
    float P00, P01, P10, P11;
    float np = 0.f;
    int tprev = tg[tbeg - 1];
    {
        float2 ea = p0[(size_t)tbeg * BB + b], eb = p1[(size_t)tbeg * BB + b];
        float e0 = ea.x + eb.x + fb0, e1 = ea.y + eb.y + fb1;
        P00 = t00 + e0; P01 = t01 + e1; P10 = t10 + e0; P11 = t11 + e1;
        int tc = tg[tbeg];
        np += (tc ? e1 : e0) + (tprev ? (tc ? t11 : t10) : (tc ? t01 : t00));
        tprev = tc;
    }
    for (int t = tbeg + 1; t < tend; ++t) {
        float2 ea = p0[(size_t)t * BB + b], eb = p1[(size_t)t * BB + b];
        float e0 = ea.x + eb.x + fb0, e1 = ea.y + eb.y + fb1;
        float n00 = lse2(P00 + t00, P01 + t10) + e0;
        float n01 = lse2(P00 + t01, P01 + t11) + e1;
        float n10 = lse2(P10 + t00, P11 + t10) + e0;
        float n11 = lse2(P10 + t01, P11 + t11) + e1;
        P00 = n00; P01 = n01; P10 = n10; P11 = n11;
        int tc = tg[t];
        np += (tc ? e1 : e0) + (tprev ? (tc ? t11 : t10) : (tc ? t01 : t00));
        tprev = tc;
    }
    __shared__ float sP[128][4];
    __shared__ float sN[128];
    sP[c][0] = P00; sP[c][1] = P01; sP[c][2] = P10; sP[c][3] = P11;
    sN[c] = np;
    __syncthreads();
    if (c == 0) {
        float2 ea = p0[b], eb = p1[b];
        float e0 = ea.x + eb.x + fb0, e1 = ea.y + eb.y + fb1;
        float a0 = crf_start[0] + e0, a1 = crf_start[1] + e1;
        float num = tg[0] ? (crf_start[1] + e1) : (crf_start[0] + e0);
        for (int k = 0; k < 128; ++k) {
            float q0 = lse2(a0 + sP[k][0], a1 + sP[k][2]);
            float q1 = lse2(a0 + sP[k][1], a1 + sP[k][3]);
            a0 = q0; a1 = q1;
            num += sN[k];
        }
        num += crf_end[tg[TT - 1]];
        float logZ = lse2(a0 + crf_end[0], a1 + crf_end[1]);
        nll_ws[b] = logZ - num;
    }
}

__global__ __launch_bounds__(128) void sum_kernel(const float* __restrict__ nll_ws,
                                                  float* __restrict__ out) {
    __shared__ float red[BB];
    red[threadIdx.x] = nll_ws[threadIdx.x];
    __syncthreads();
    if (threadIdx.x == 0) {
        float s = 0.f;
        for (int i = 0; i < BB; ++i) s += red[i];
        out[0] = s;
    }
}

extern "C" void kernel_launch(void* const* d_in, const int* in_sizes, int n_in,
                              void* d_out, int out_size, void* d_ws, size_t ws_size,
                              hipStream_t stream) {
    const float* x = (const float*)d_in[0];
    const int* tags = (const int*)d_in[1];
    const float* cw1 = (const float*)d_in[2];
    const float* cb1 = (const float*)d_in[3];
    const float* cwr = (const float*)d_in[4];
    const float* cbr = (const float*)d_in[5];
    const float* bn_g = (const float*)d_in[6];
    const float* bn_b = (const float*)d_in[7];
    const float* bn_m = (const float*)d_in[8];
    const float* bn_v = (const float*)d_in[9];
    const float* wih_f = (const float*)d_in[10];
    const float* whh_f = (const float*)d_in[11];
    const float* bih_f = (const float*)d_in[12];
    const float* bhh_f = (const float*)d_in[13];
    const float* wih_b = (const float*)d_in[14];
    const float* whh_b = (const float*)d_in[15];
    const float* bih_b = (const float*)d_in[16];
    const float* bhh_b = (const float*)d_in[17];
    const float* fc_w = (const float*)d_in[18];
    const float* fc_b = (const float*)d_in[19];
    const float* crf_start = (const float*)d_in[20];
    const float* crf_end = (const float*)d_in[21];
    const float* crf_trans = (const float*)d_in[22];
    float* out = (float*)d_out;

    ushort_t* y = (ushort_t*)d_ws;                                     // 32 MiB
    float* em = (float*)((char*)d_ws + (size_t)BT * 64 * 2);           // 4 MiB
    float* nll = (float*)((char*)d_ws + (size_t)BT * 64 * 2 + (size_t)2 * TT * BB * 2 * 4);

    conv_kernel<<<1024, 256, 0, stream>>>(x, cw1, cb1, cwr, cbr, bn_g, bn_b, bn_m, bn_v, y);
    lstm_kernel<<<256, 64, 0, stream>>>(y, whh_f, whh_b, wih_f, wih_b,
                                        bih_f, bhh_f, bih_b, bhh_b, fc_w, em);
    crf_kernel<<<128, 128, 0, stream>>>(em, tags, fc_b, crf_start, crf_end, crf_trans, nll);
    sum_kernel<<<1, 128, 0, stream>>>(nll, out);
}